// Round 1
// baseline (253.473 us; speedup 1.0000x reference)
//
#include <hip/hip_runtime.h>
#include <hip/hip_bf16.h>

#define NROWS 6144
#define MCOLS 6144
#define DDIM  128
#define EPSQ  1e-12f

typedef unsigned long long ull;

// Order-preserving key: max key == max float value, ties -> smallest index
// (matches numpy argmax first-occurrence semantics).
__device__ __forceinline__ ull makeKey(float v, int idx) {
    unsigned u = __float_as_uint(v);
    u = (u & 0x80000000u) ? ~u : (u | 0x80000000u);
    return ((ull)u << 32) | (ull)(0xFFFFFFFFu - (unsigned)idx);
}

__device__ __forceinline__ int decodeKeyIdx(ull k) {
    return (int)(0xFFFFFFFFu - (unsigned)(k & 0xFFFFFFFFull));
}

__device__ __forceinline__ ull shflXorU64(ull v, int m) {
    unsigned lo = (unsigned)(v & 0xFFFFFFFFull);
    unsigned hi = (unsigned)(v >> 32);
    lo = __shfl_xor(lo, m, 64);
    hi = __shfl_xor(hi, m, 64);
    return (((ull)hi) << 32) | (ull)lo;
}

// ---------------- K0: squared norms of each descriptor row ----------------
__global__ __launch_bounds__(256) void sqnorm_kernel(
    const float* __restrict__ d1, const float* __restrict__ d2,
    float* __restrict__ sq1, float* __restrict__ sq2)
{
    int gwave = (blockIdx.x * 256 + threadIdx.x) >> 6;   // one wave per row
    int lane  = threadIdx.x & 63;
    if (gwave >= NROWS + MCOLS) return;
    const float* p = (gwave < NROWS) ? (d1 + (size_t)gwave * DDIM)
                                     : (d2 + (size_t)(gwave - NROWS) * DDIM);
    float2 v = *(const float2*)(p + lane * 2);
    float s = v.x * v.x + v.y * v.y;
    #pragma unroll
    for (int m = 1; m < 64; m <<= 1) s += __shfl_xor(s, m, 64);
    if (lane == 0) {
        if (gwave < NROWS) sq1[gwave] = s;
        else               sq2[gwave - NROWS] = s;
    }
}

// ---------------- K1: f32 GEMM -> affinity -> fused row/col reductions ----
// 128x128 tile per 256-thread block; 8x8 acc per thread; BK=16.
__global__ __launch_bounds__(256) void gemm_affinity_kernel(
    const float* __restrict__ d1, const float* __restrict__ d2,
    const float* __restrict__ invT,
    const float* __restrict__ sq1, const float* __restrict__ sq2,
    float* __restrict__ aff_out,            // [N][M] scratch = dense_logp region
    float* __restrict__ rowsum, float* __restrict__ colsum,
    ull* __restrict__ rowkey,   ull* __restrict__ colkey)
{
    __shared__ float As[16][128];   // k-major
    __shared__ float Bs[16][128];
    __shared__ float cS[4][128];
    __shared__ ull   cK[4][128];

    const int t  = threadIdx.x;
    const int tx = t & 15;          // col group
    const int ty = t >> 4;          // row group
    const int rowBase = blockIdx.y * 128;
    const int colBase = blockIdx.x * 128;

    float acc[8][8];
    #pragma unroll
    for (int i = 0; i < 8; ++i)
        #pragma unroll
        for (int j = 0; j < 8; ++j) acc[i][j] = 0.0f;

    for (int ks = 0; ks < 8; ++ks) {
        const int k0 = ks * 16;
        #pragma unroll
        for (int r = 0; r < 2; ++r) {
            int idx = t + r * 256;          // 0..511
            int row = idx >> 2;             // 0..127
            int kq  = (idx & 3) << 2;       // 0,4,8,12
            float4 va = *(const float4*)(d1 + (size_t)(rowBase + row) * DDIM + k0 + kq);
            As[kq + 0][row] = va.x; As[kq + 1][row] = va.y;
            As[kq + 2][row] = va.z; As[kq + 3][row] = va.w;
            float4 vb = *(const float4*)(d2 + (size_t)(colBase + row) * DDIM + k0 + kq);
            Bs[kq + 0][row] = vb.x; Bs[kq + 1][row] = vb.y;
            Bs[kq + 2][row] = vb.z; Bs[kq + 3][row] = vb.w;
        }
        __syncthreads();
        #pragma unroll
        for (int k = 0; k < 16; ++k) {
            float a[8], b[8];
            *(float4*)&a[0] = *(const float4*)&As[k][ty * 4];
            *(float4*)&a[4] = *(const float4*)&As[k][ty * 4 + 64];
            *(float4*)&b[0] = *(const float4*)&Bs[k][tx * 4];
            *(float4*)&b[4] = *(const float4*)&Bs[k][tx * 4 + 64];
            #pragma unroll
            for (int i = 0; i < 8; ++i)
                #pragma unroll
                for (int j = 0; j < 8; ++j)
                    acc[i][j] = fmaf(a[i], b[j], acc[i][j]);
        }
        __syncthreads();
    }

    // ---- epilogue: affinity ----
    const float iT = *invT;
    float s1v[8], s2v[8];
    int rIdx[8], cIdx[8];
    #pragma unroll
    for (int i = 0; i < 8; ++i) {
        int rl = (i >> 2) * 64 + ty * 4 + (i & 3);
        int cl = (i >> 2) * 64 + tx * 4 + (i & 3);
        rIdx[i] = rl;  cIdx[i] = cl;
        s1v[i] = sq1[rowBase + rl];
        s2v[i] = sq2[colBase + cl];
    }
    #pragma unroll
    for (int i = 0; i < 8; ++i) {
        #pragma unroll
        for (int j = 0; j < 8; ++j) {
            float dd = s1v[i] + s2v[j] - 2.0f * acc[i][j];
            acc[i][j] = -iT * sqrtf(fmaxf(dd, 0.0f) + EPSQ);
        }
        float4 lo = make_float4(acc[i][0], acc[i][1], acc[i][2], acc[i][3]);
        float4 hi = make_float4(acc[i][4], acc[i][5], acc[i][6], acc[i][7]);
        size_t rowoff = (size_t)(rowBase + rIdx[i]) * MCOLS + colBase;
        *(float4*)(aff_out + rowoff + tx * 4) = lo;
        *(float4*)(aff_out + rowoff + 64 + tx * 4) = hi;
    }

    // ---- row reduction: 16 lanes (tx) share each row ----
    #pragma unroll
    for (int i = 0; i < 8; ++i) {
        float s = 0.0f; ull k = 0ull;
        #pragma unroll
        for (int j = 0; j < 8; ++j) {
            s += expf(acc[i][j]);
            ull kk = makeKey(acc[i][j], colBase + cIdx[j]);
            k = kk > k ? kk : k;
        }
        #pragma unroll
        for (int m = 1; m < 16; m <<= 1) {
            s += __shfl_xor(s, m, 64);
            ull ko = shflXorU64(k, m);
            k = ko > k ? ko : k;
        }
        if (tx == 0) {
            atomicAdd(&rowsum[rowBase + rIdx[i]], s);
            atomicMax(&rowkey[rowBase + rIdx[i]], k);
        }
    }

    // ---- col reduction: 16 ty-threads share each col (4 in-wave, 4 waves) ----
    float csv[8]; ull ckv[8];
    #pragma unroll
    for (int j = 0; j < 8; ++j) {
        float s = 0.0f; ull k = 0ull;
        #pragma unroll
        for (int i = 0; i < 8; ++i) {
            s += expf(acc[i][j]);
            ull kk = makeKey(acc[i][j], rowBase + rIdx[i]);
            k = kk > k ? kk : k;
        }
        // reduce over ty%4 (lanes differing in bits 4,5)
        s += __shfl_xor(s, 16, 64); { ull ko = shflXorU64(k, 16); k = ko > k ? ko : k; }
        s += __shfl_xor(s, 32, 64); { ull ko = shflXorU64(k, 32); k = ko > k ? ko : k; }
        csv[j] = s; ckv[j] = k;
    }
    int w = t >> 6;
    if ((ty & 3) == 0) {
        #pragma unroll
        for (int j = 0; j < 8; ++j) {
            cS[w][cIdx[j]] = csv[j];
            cK[w][cIdx[j]] = ckv[j];
        }
    }
    __syncthreads();
    if (t < 128) {
        float s = cS[0][t] + cS[1][t] + cS[2][t] + cS[3][t];
        ull k = cK[0][t];
        if (cK[1][t] > k) k = cK[1][t];
        if (cK[2][t] > k) k = cK[2][t];
        if (cK[3][t] > k) k = cK[3][t];
        atomicAdd(&colsum[colBase + t], s);
        atomicMax(&colkey[colBase + t], k);
    }
}

// ---------------- K2a: per-column LSE + argmax decode ----------------
__global__ __launch_bounds__(256) void finalize_cols_kernel(
    const float* __restrict__ colsum, const ull* __restrict__ colkey,
    float* __restrict__ collse, int* __restrict__ maxesT)
{
    int j = blockIdx.x * 256 + threadIdx.x;
    if (j >= MCOLS) return;
    collse[j] = logf(colsum[j]);
    maxesT[j] = decodeKeyIdx(colkey[j]);
}

// ---------------- K2b: per-row LSE + matches + cycle ----------------
__global__ __launch_bounds__(256) void finalize_rows_kernel(
    const float* __restrict__ rowsum, const ull* __restrict__ rowkey,
    const int* __restrict__ maxesT,
    float* __restrict__ rowlse,
    float* __restrict__ out_matches,   // [2][N] as float
    float* __restrict__ out_cyc)       // [N] as float 0/1
{
    int i = blockIdx.x * 256 + threadIdx.x;
    if (i >= NROWS) return;
    rowlse[i] = logf(rowsum[i]);
    int mi = decodeKeyIdx(rowkey[i]);
    out_matches[i]          = (float)i;
    out_matches[NROWS + i]  = (float)mi;
    out_cyc[i] = (maxesT[mi] == i) ? 1.0f : 0.0f;
}

// ---------------- K3: dense_logp (in place) + dense_p ----------------
__global__ __launch_bounds__(256) void finalize_mat_kernel(
    float* __restrict__ aff_logp,          // read affinity, write logp
    float* __restrict__ p_out,
    const float* __restrict__ rowlse, const float* __restrict__ collse)
{
    size_t tid = (size_t)blockIdx.x * 256 + threadIdx.x;   // one float4 each
    int jq = (int)(tid % (MCOLS / 4));
    int i  = (int)(tid / (MCOLS / 4));
    float rl = rowlse[i];
    float4 cl = *(const float4*)(collse + jq * 4);
    float4 a  = *(float4*)(aff_logp + tid * 4);
    float4 o, p;
    o.x = (a.x - rl) + (a.x - cl.x); p.x = expf(o.x);
    o.y = (a.y - rl) + (a.y - cl.y); p.y = expf(o.y);
    o.z = (a.z - rl) + (a.z - cl.z); p.z = expf(o.z);
    o.w = (a.w - rl) + (a.w - cl.w); p.w = expf(o.w);
    *(float4*)(aff_logp + tid * 4) = o;
    *(float4*)(p_out + tid * 4)    = p;
}

extern "C" void kernel_launch(void* const* d_in, const int* in_sizes, int n_in,
                              void* d_out, int out_size, void* d_ws, size_t ws_size,
                              hipStream_t stream) {
    const float* d1   = (const float*)d_in[0];
    const float* d2   = (const float*)d_in[1];
    const float* invT = (const float*)d_in[2];

    float* out     = (float*)d_out;
    float* aff     = out;                                   // dense_logp region (scratch then final)
    float* pout    = out + (size_t)NROWS * MCOLS;
    float* matches = out + 2ull * NROWS * MCOLS;
    float* cyc     = matches + 2 * NROWS;

    char* ws = (char*)d_ws;
    float* rowsum = (float*)(ws + 0);                       // N f32
    float* colsum = (float*)(ws + 24576);                   // M f32
    ull*   rowkey = (ull*)(ws + 49152);                     // N u64
    ull*   colkey = (ull*)(ws + 98304);                     // M u64
    float* sq1    = (float*)(ws + 147456);                  // N f32
    float* sq2    = (float*)(ws + 172032);                  // M f32
    float* rowlse = (float*)(ws + 196608);                  // N f32
    float* collse = (float*)(ws + 221184);                  // M f32
    int*   maxesT = (int*)  (ws + 245760);                  // M i32

    // zero the atomic accumulators (rowsum, colsum, rowkey, colkey)
    hipMemsetAsync(d_ws, 0, 147456, stream);

    sqnorm_kernel<<<(NROWS + MCOLS) / 4, 256, 0, stream>>>(d1, d2, sq1, sq2);

    dim3 grid(MCOLS / 128, NROWS / 128);
    gemm_affinity_kernel<<<grid, 256, 0, stream>>>(
        d1, d2, invT, sq1, sq2, aff, rowsum, colsum, rowkey, colkey);

    finalize_cols_kernel<<<MCOLS / 256, 256, 0, stream>>>(colsum, colkey, collse, maxesT);
    finalize_rows_kernel<<<NROWS / 256, 256, 0, stream>>>(rowsum, rowkey, maxesT, rowlse,
                                                          matches, cyc);

    finalize_mat_kernel<<<(size_t)NROWS * MCOLS / 4 / 256, 256, 0, stream>>>(
        aff, pout, rowlse, collse);
}

// Round 2
// 235.459 us; speedup vs baseline: 1.0765x; 1.0765x over previous
//
#include <hip/hip_runtime.h>
#include <hip/hip_bf16.h>
#include <stdint.h>

#define NROWS 6144
#define MCOLS 6144
#define DDIM  128
#define EPSQ  1e-12f

typedef unsigned long long ull;
typedef __attribute__((ext_vector_type(8))) short short8;
typedef __attribute__((ext_vector_type(4))) float floatx4;

// Order-preserving key: max key == max float value, ties -> smallest index.
__device__ __forceinline__ ull makeKey(float v, int idx) {
    unsigned u = __float_as_uint(v);
    u = (u & 0x80000000u) ? ~u : (u | 0x80000000u);
    return ((ull)u << 32) | (ull)(0xFFFFFFFFu - (unsigned)idx);
}
__device__ __forceinline__ int decodeKeyIdx(ull k) {
    return (int)(0xFFFFFFFFu - (unsigned)(k & 0xFFFFFFFFull));
}
__device__ __forceinline__ unsigned short f2bf(float f) {   // RNE, no NaN handling needed
    unsigned u = __float_as_uint(f);
    u += 0x7fffu + ((u >> 16) & 1);
    return (unsigned short)(u >> 16);
}

#define GLOAD16(g, l) \
  __builtin_amdgcn_global_load_lds((const __attribute__((address_space(1))) unsigned int*)(g), \
                                   (__attribute__((address_space(3))) unsigned int*)(l), 16, 0, 0)

// ---------------- K0: convert to pre-swizzled bf16 hi|lo panels + sqnorms ----
// Output layout: [row][256] bf16; elems 0-127 = hi(k), 128-255 = lo(k),
// element position XOR-swizzled: p = k ^ ((row&7)<<3)  (== byte ^ ((row&7)<<4)).
__global__ __launch_bounds__(256) void convert_kernel(
    const float* __restrict__ d1, const float* __restrict__ d2,
    unsigned short* __restrict__ s1, unsigned short* __restrict__ s2,
    float* __restrict__ sq1, float* __restrict__ sq2)
{
    int gw = (blockIdx.x * 256 + threadIdx.x) >> 6;   // one wave per row
    int lane = threadIdx.x & 63;
    if (gw >= NROWS + MCOLS) return;
    bool isA = gw < NROWS;
    int row = isA ? gw : gw - NROWS;
    const float* src = (isA ? d1 : d2) + (size_t)row * DDIM;
    unsigned short* dst = (isA ? s1 : s2) + (size_t)row * 256;

    float2 v = *(const float2*)(src + lane * 2);
    float s = v.x * v.x + v.y * v.y;
    #pragma unroll
    for (int m = 1; m < 64; m <<= 1) s += __shfl_xor(s, m, 64);
    if (lane == 0) { if (isA) sq1[row] = s; else sq2[row] = s; }

    unsigned short h0 = f2bf(v.x), h1 = f2bf(v.y);
    float r0 = v.x - __uint_as_float((unsigned)h0 << 16);
    float r1 = v.y - __uint_as_float((unsigned)h1 << 16);
    unsigned short l0 = f2bf(r0), l1 = f2bf(r1);
    int p = (2 * lane) ^ ((row & 7) << 3);            // pair stays adjacent (xor bits 3-5)
    *(unsigned*)(dst + p)       = (unsigned)h0 | ((unsigned)h1 << 16);
    *(unsigned*)(dst + p + 128) = (unsigned)l0 | ((unsigned)l1 << 16);
}

// ---------------- K1: MFMA bf16 split GEMM -> affinity -> fused reductions ----
// 128x128 tile, 512 threads = 8 waves (2 row-halves x 4 col-quarters),
// wave tile 64x32 = 4x2 frags of 16x16. K = 3 passes of 128 (hh, lh, hl).
__global__ __launch_bounds__(512) void gemm_affinity_kernel(
    const unsigned short* __restrict__ s1, const unsigned short* __restrict__ s2,
    const float* __restrict__ invT,
    const float* __restrict__ sq1, const float* __restrict__ sq2,
    float* __restrict__ aff_out,
    float* __restrict__ rowsum, float* __restrict__ colsum,
    ull* __restrict__ rowkey, ull* __restrict__ colkey)
{
    __shared__ unsigned short As[128 * 256];   // 64 KB, swizzled rows
    __shared__ unsigned short Bs[128 * 256];   // 64 KB
    __shared__ float lRowS[128], lColS[128];
    __shared__ ull   lRowK[128], lColK[128];

    const int t = threadIdx.x;
    const int lane = t & 63;
    const int wave = t >> 6;
    const int wr = wave >> 2;        // 0..1
    const int wc = wave & 3;         // 0..3
    const int rowBase = blockIdx.y * 128;
    const int colBase = blockIdx.x * 128;

    if (t < 128) { lRowS[t] = 0.f; lColS[t] = 0.f; lRowK[t] = 0ull; lColK[t] = 0ull; }

    // ---- one-shot staging: pre-swizzled global -> linear LDS (16B/lane) ----
    {
        const unsigned short* gA = s1 + (size_t)rowBase * 256;
        const unsigned short* gB = s2 + (size_t)colBase * 256;
        int wb = wave * 512;                      // 1 KB per wave per round
        #pragma unroll
        for (int it = 0; it < 8; ++it) {
            int e = wb + it * 4096;
            GLOAD16(gA + e + lane * 8, &As[e]);
            GLOAD16(gB + e + lane * 8, &Bs[e]);
        }
    }
    __syncthreads();

    // ---- MFMA main loop ----
    const int l15 = lane & 15;
    const int kpl = (lane >> 4) * 16;     // byte offset of this lane's k-chunk
    const int sw  = (lane & 7) << 4;      // xor swizzle (row&7 == lane&7 here)
    int aRowB[4], bRowB[2];
    #pragma unroll
    for (int mi = 0; mi < 4; ++mi) aRowB[mi] = (wr * 64 + mi * 16 + l15) * 512;
    #pragma unroll
    for (int ni = 0; ni < 2; ++ni) bRowB[ni] = (wc * 32 + ni * 16 + l15) * 512;

    floatx4 acc[4][2] = {};
    const char* Ab = (const char*)As;
    const char* Bb = (const char*)Bs;
    #pragma unroll
    for (int p = 0; p < 3; ++p) {
        const int Aoff = (p == 1) ? 256 : 0;   // byte offset: lo half of A
        const int Boff = (p == 2) ? 256 : 0;   // byte offset: lo half of B
        #pragma unroll
        for (int ks = 0; ks < 4; ++ks) {
            const int kk = (ks * 64 + kpl) ^ sw;
            short8 af[4], bf[2];
            #pragma unroll
            for (int mi = 0; mi < 4; ++mi)
                af[mi] = *(const short8*)(Ab + aRowB[mi] + Aoff + kk);
            #pragma unroll
            for (int ni = 0; ni < 2; ++ni)
                bf[ni] = *(const short8*)(Bb + bRowB[ni] + Boff + kk);
            #pragma unroll
            for (int mi = 0; mi < 4; ++mi)
                #pragma unroll
                for (int ni = 0; ni < 2; ++ni)
                    acc[mi][ni] = __builtin_amdgcn_mfma_f32_16x16x32_bf16(
                        af[mi], bf[ni], acc[mi][ni], 0, 0, 0);
        }
    }

    // ---- epilogue: affinity + exp + row/col partial reductions ----
    const float iT = *invT;
    int gcol[2]; float s2v[2];
    #pragma unroll
    for (int ni = 0; ni < 2; ++ni) {
        gcol[ni] = colBase + wc * 32 + ni * 16 + l15;
        s2v[ni] = sq2[gcol[ni]];
    }
    float rs[4][4], rv[4][4]; int ri[4][4];
    float cs[2] = {0.f, 0.f}, cv[2] = {-1e30f, -1e30f}; int ci[2] = {0, 0};

    #pragma unroll
    for (int mi = 0; mi < 4; ++mi) {
        int grow0 = rowBase + wr * 64 + mi * 16 + (lane >> 4) * 4;
        float s1r[4];
        #pragma unroll
        for (int r = 0; r < 4; ++r) s1r[r] = sq1[grow0 + r];
        #pragma unroll
        for (int r = 0; r < 4; ++r) { rs[mi][r] = 0.f; rv[mi][r] = -1e30f; ri[mi][r] = 0; }
        #pragma unroll
        for (int ni = 0; ni < 2; ++ni) {
            #pragma unroll
            for (int r = 0; r < 4; ++r) {
                float dd = s1r[r] + s2v[ni] - 2.0f * acc[mi][ni][r];
                float v = -iT * sqrtf(fmaxf(dd, 0.0f) + EPSQ);
                aff_out[(size_t)(grow0 + r) * MCOLS + gcol[ni]] = v;
                float e = expf(v);
                rs[mi][r] += e;
                if (v > rv[mi][r]) { rv[mi][r] = v; ri[mi][r] = gcol[ni]; }
                cs[ni] += e;
                int grow = grow0 + r;
                if (v > cv[ni] || (v == cv[ni] && grow < ci[ni])) { cv[ni] = v; ci[ni] = grow; }
            }
        }
    }

    // row reduce across the 16-lane col group
    #pragma unroll
    for (int mi = 0; mi < 4; ++mi)
        #pragma unroll
        for (int r = 0; r < 4; ++r) {
            float s = rs[mi][r], v = rv[mi][r]; int i = ri[mi][r];
            #pragma unroll
            for (int m = 1; m < 16; m <<= 1) {
                s += __shfl_xor(s, m, 64);
                float ov = __shfl_xor(v, m, 64);
                int oi = __shfl_xor(i, m, 64);
                if (ov > v || (ov == v && oi < i)) { v = ov; i = oi; }
            }
            if (l15 == 0) {
                int idx = wr * 64 + mi * 16 + (lane >> 4) * 4 + r;
                atomicAdd(&lRowS[idx], s);
                atomicMax(&lRowK[idx], makeKey(v, i));
            }
        }

    // col reduce across the 4 row groups within the wave
    #pragma unroll
    for (int ni = 0; ni < 2; ++ni) {
        float s = cs[ni], v = cv[ni]; int i = ci[ni];
        #pragma unroll
        for (int m = 16; m < 64; m <<= 1) {
            s += __shfl_xor(s, m, 64);
            float ov = __shfl_xor(v, m, 64);
            int oi = __shfl_xor(i, m, 64);
            if (ov > v || (ov == v && oi < i)) { v = ov; i = oi; }
        }
        if (lane < 16) {
            int idx = wc * 32 + ni * 16 + lane;
            atomicAdd(&lColS[idx], s);
            atomicMax(&lColK[idx], makeKey(v, i));
        }
    }
    __syncthreads();

    if (t < 128) {
        atomicAdd(&rowsum[rowBase + t], lRowS[t]);
        atomicMax(&rowkey[rowBase + t], lRowK[t]);
    } else if (t < 256) {
        int j = t - 128;
        atomicAdd(&colsum[colBase + j], lColS[j]);
        atomicMax(&colkey[colBase + j], lColK[j]);
    }
}

// ---------------- K2a: per-column LSE + argmax decode ----------------
__global__ __launch_bounds__(256) void finalize_cols_kernel(
    const float* __restrict__ colsum, const ull* __restrict__ colkey,
    float* __restrict__ collse, int* __restrict__ maxesT)
{
    int j = blockIdx.x * 256 + threadIdx.x;
    if (j >= MCOLS) return;
    collse[j] = logf(colsum[j]);
    maxesT[j] = decodeKeyIdx(colkey[j]);
}

// ---------------- K2b: per-row LSE + matches + cycle ----------------
__global__ __launch_bounds__(256) void finalize_rows_kernel(
    const float* __restrict__ rowsum, const ull* __restrict__ rowkey,
    const int* __restrict__ maxesT,
    float* __restrict__ rowlse,
    float* __restrict__ out_matches, float* __restrict__ out_cyc)
{
    int i = blockIdx.x * 256 + threadIdx.x;
    if (i >= NROWS) return;
    rowlse[i] = logf(rowsum[i]);
    int mi = decodeKeyIdx(rowkey[i]);
    out_matches[i]         = (float)i;
    out_matches[NROWS + i] = (float)mi;
    out_cyc[i] = (maxesT[mi] == i) ? 1.0f : 0.0f;
}

// ---------------- K3: dense_logp (in place) + dense_p ----------------
__global__ __launch_bounds__(256) void finalize_mat_kernel(
    float* __restrict__ aff_logp, float* __restrict__ p_out,
    const float* __restrict__ rowlse, const float* __restrict__ collse)
{
    size_t tid = (size_t)blockIdx.x * 256 + threadIdx.x;   // one float4 each
    int jq = (int)(tid % (MCOLS / 4));
    int i  = (int)(tid / (MCOLS / 4));
    float rl = rowlse[i];
    float4 cl = *(const float4*)(collse + jq * 4);
    float4 a  = *(float4*)(aff_logp + tid * 4);
    float4 o, p;
    o.x = (a.x - rl) + (a.x - cl.x); p.x = expf(o.x);
    o.y = (a.y - rl) + (a.y - cl.y); p.y = expf(o.y);
    o.z = (a.z - rl) + (a.z - cl.z); p.z = expf(o.z);
    o.w = (a.w - rl) + (a.w - cl.w); p.w = expf(o.w);
    *(float4*)(aff_logp + tid * 4) = o;
    *(float4*)(p_out + tid * 4)    = p;
}

extern "C" void kernel_launch(void* const* d_in, const int* in_sizes, int n_in,
                              void* d_out, int out_size, void* d_ws, size_t ws_size,
                              hipStream_t stream) {
    const float* d1   = (const float*)d_in[0];
    const float* d2   = (const float*)d_in[1];
    const float* invT = (const float*)d_in[2];

    float* out     = (float*)d_out;
    float* aff     = out;                              // dense_logp region (scratch then final)
    float* pout    = out + (size_t)NROWS * MCOLS;
    float* matches = out + 2ull * NROWS * MCOLS;
    float* cyc     = matches + 2 * NROWS;

    char* ws = (char*)d_ws;
    float* rowsum = (float*)(ws + 0);                  // N f32
    float* colsum = (float*)(ws + 24576);              // M f32
    ull*   rowkey = (ull*)(ws + 49152);                // N u64
    ull*   colkey = (ull*)(ws + 98304);                // M u64
    float* sq1    = (float*)(ws + 147456);
    float* sq2    = (float*)(ws + 172032);
    float* rowlse = (float*)(ws + 196608);
    float* collse = (float*)(ws + 221184);
    int*   maxesT = (int*)  (ws + 245760);
    unsigned short* s1 = (unsigned short*)(ws + 270336);            // [N][256] bf16
    unsigned short* s2 = (unsigned short*)(ws + 270336 + 3145728);  // [M][256] bf16

    hipMemsetAsync(d_ws, 0, 147456, stream);           // rowsum/colsum/rowkey/colkey

    convert_kernel<<<(NROWS + MCOLS) / 4, 256, 0, stream>>>(d1, d2, s1, s2, sq1, sq2);

    dim3 grid(MCOLS / 128, NROWS / 128);
    gemm_affinity_kernel<<<grid, 512, 0, stream>>>(
        s1, s2, invT, sq1, sq2, aff, rowsum, colsum, rowkey, colkey);

    finalize_cols_kernel<<<MCOLS / 256, 256, 0, stream>>>(colsum, colkey, collse, maxesT);
    finalize_rows_kernel<<<NROWS / 256, 256, 0, stream>>>(rowsum, rowkey, maxesT, rowlse,
                                                          matches, cyc);

    finalize_mat_kernel<<<(size_t)NROWS * MCOLS / 4 / 256, 256, 0, stream>>>(
        aff, pout, rowlse, collse);
}

// Round 3
// 183.520 us; speedup vs baseline: 1.3812x; 1.2830x over previous
//
#include <hip/hip_runtime.h>
#include <hip/hip_bf16.h>
#include <stdint.h>

#define NROWS 6144
#define MCOLS 6144
#define DDIM  128
#define EPSQ  1e-12f

typedef unsigned long long ull;
typedef __attribute__((ext_vector_type(8))) short short8;
typedef __attribute__((ext_vector_type(4))) float floatx4;

// Order-preserving key: max key == max float value, ties -> smallest index.
__device__ __forceinline__ ull makeKey(float v, int idx) {
    unsigned u = __float_as_uint(v);
    u = (u & 0x80000000u) ? ~u : (u | 0x80000000u);
    return ((ull)u << 32) | (ull)(0xFFFFFFFFu - (unsigned)idx);
}
__device__ __forceinline__ int decodeKeyIdx(ull k) {
    return (int)(0xFFFFFFFFu - (unsigned)(k & 0xFFFFFFFFull));
}
__device__ __forceinline__ unsigned short f2bf(float f) {   // RNE
    unsigned u = __float_as_uint(f);
    u += 0x7fffu + ((u >> 16) & 1);
    return (unsigned short)(u >> 16);
}

#define GLOAD16(g, l) \
  __builtin_amdgcn_global_load_lds((const __attribute__((address_space(1))) unsigned int*)(g), \
                                   (__attribute__((address_space(3))) unsigned int*)(l), 16, 0, 0)

// ---------------- K0: convert to pre-swizzled bf16 hi|lo panels + sqnorms ----
// [row][256] bf16; elems 0-127 = hi(k), 128-255 = lo(k); pos p = k ^ ((row&7)<<3).
__global__ __launch_bounds__(256) void convert_kernel(
    const float* __restrict__ d1, const float* __restrict__ d2,
    unsigned short* __restrict__ s1, unsigned short* __restrict__ s2,
    float* __restrict__ sq1, float* __restrict__ sq2)
{
    int gw = (blockIdx.x * 256 + threadIdx.x) >> 6;   // one wave per row
    int lane = threadIdx.x & 63;
    if (gw >= NROWS + MCOLS) return;
    bool isA = gw < NROWS;
    int row = isA ? gw : gw - NROWS;
    const float* src = (isA ? d1 : d2) + (size_t)row * DDIM;
    unsigned short* dst = (isA ? s1 : s2) + (size_t)row * 256;

    float2 v = *(const float2*)(src + lane * 2);
    float s = v.x * v.x + v.y * v.y;
    #pragma unroll
    for (int m = 1; m < 64; m <<= 1) s += __shfl_xor(s, m, 64);
    if (lane == 0) { if (isA) sq1[row] = s; else sq2[row] = s; }

    unsigned short h0 = f2bf(v.x), h1 = f2bf(v.y);
    float r0 = v.x - __uint_as_float((unsigned)h0 << 16);
    float r1 = v.y - __uint_as_float((unsigned)h1 << 16);
    unsigned short l0 = f2bf(r0), l1 = f2bf(r1);
    int p = (2 * lane) ^ ((row & 7) << 3);            // pair stays adjacent
    *(unsigned*)(dst + p)       = (unsigned)h0 | ((unsigned)h1 << 16);
    *(unsigned*)(dst + p + 128) = (unsigned)l0 | ((unsigned)l1 << 16);
}

// ---------------- K1: MFMA bf16 split GEMM -> affinity -> fused reductions ----
// 128x128 tile, 512 threads = 8 waves (wr 0..1 x wc 0..3), wave tile 64x32.
// SWAPPED operands: mfma(B,A) => lane holds row=l15, cols=(lane>>4)*4+reg.
__global__ __launch_bounds__(512) void gemm_affinity_kernel(
    const unsigned short* __restrict__ s1, const unsigned short* __restrict__ s2,
    const float* __restrict__ invT,
    const float* __restrict__ sq1, const float* __restrict__ sq2,
    float* __restrict__ aff_out,
    float* __restrict__ rowsum, float* __restrict__ colsum,
    ull* __restrict__ rowkey, ull* __restrict__ colkey)
{
    __shared__ unsigned short As[128 * 256];   // 64 KB
    __shared__ unsigned short Bs[128 * 256];   // 64 KB
    __shared__ float lRowS[128], lColS[128];
    __shared__ ull   lRowK[128], lColK[128];

    const int t = threadIdx.x;
    const int lane = t & 63;
    const int wave = t >> 6;
    const int wr = wave >> 2;        // 0..1
    const int wc = wave & 3;         // 0..3
    const int rowBase = blockIdx.y * 128;
    const int colBase = blockIdx.x * 128;

    if (t < 128) { lRowS[t] = 0.f; lColS[t] = 0.f; lRowK[t] = 0ull; lColK[t] = 0ull; }

    // ---- one-shot staging: pre-swizzled global -> linear LDS (16B/lane) ----
    {
        const unsigned short* gA = s1 + (size_t)rowBase * 256;
        const unsigned short* gB = s2 + (size_t)colBase * 256;
        int wb = wave * 512;
        #pragma unroll
        for (int it = 0; it < 8; ++it) {
            int e = wb + it * 4096;
            GLOAD16(gA + e + lane * 8, &As[e]);
            GLOAD16(gB + e + lane * 8, &Bs[e]);
        }
    }
    __syncthreads();

    // ---- MFMA main loop ----
    const int l15 = lane & 15;
    const int q   = lane >> 4;            // 0..3 col-quarter
    const int kpl = q * 16;               // byte offset of lane's k-chunk
    const int sw  = (lane & 7) << 4;      // xor swizzle
    int aRowB[4], bRowB[2];
    #pragma unroll
    for (int mi = 0; mi < 4; ++mi) aRowB[mi] = (wr * 64 + mi * 16 + l15) * 512;
    #pragma unroll
    for (int ni = 0; ni < 2; ++ni) bRowB[ni] = (wc * 32 + ni * 16 + l15) * 512;

    floatx4 acc[4][2] = {};
    const char* Ab = (const char*)As;
    const char* Bb = (const char*)Bs;
    #pragma unroll
    for (int p = 0; p < 3; ++p) {
        const int Aoff = (p == 1) ? 256 : 0;   // lo half of A (bytes)
        const int Boff = (p == 2) ? 256 : 0;   // lo half of B
        #pragma unroll
        for (int ks = 0; ks < 4; ++ks) {
            const int kk = (ks * 64 + kpl) ^ sw;
            short8 af[4], bf[2];
            #pragma unroll
            for (int mi = 0; mi < 4; ++mi)
                af[mi] = *(const short8*)(Ab + aRowB[mi] + Aoff + kk);
            #pragma unroll
            for (int ni = 0; ni < 2; ++ni)
                bf[ni] = *(const short8*)(Bb + bRowB[ni] + Boff + kk);
            #pragma unroll
            for (int mi = 0; mi < 4; ++mi)
                #pragma unroll
                for (int ni = 0; ni < 2; ++ni)
                    acc[mi][ni] = __builtin_amdgcn_mfma_f32_16x16x32_bf16(
                        bf[ni], af[mi], acc[mi][ni], 0, 0, 0);   // SWAPPED
        }
    }

    // ---- epilogue ----
    // lane's rows: i(mi) = rowBase + wr*64 + mi*16 + l15
    // lane's cols: j(ni,r) = colBase + wc*32 + ni*16 + q*4 + r
    const float iT = *invT;
    float s1r[4];
    #pragma unroll
    for (int mi = 0; mi < 4; ++mi) s1r[mi] = sq1[rowBase + wr * 64 + mi * 16 + l15];
    const int colLoc0 = wc * 32 + q * 4;
    float4 s2v[2];
    #pragma unroll
    for (int ni = 0; ni < 2; ++ni)
        s2v[ni] = *(const float4*)(sq2 + colBase + colLoc0 + ni * 16);

    float rs[4], rv[4]; int rj[4];
    float cs[2][4], cv[2][4]; int ci[2][4];
    #pragma unroll
    for (int ni = 0; ni < 2; ++ni)
        #pragma unroll
        for (int r = 0; r < 4; ++r) { cs[ni][r] = 0.f; cv[ni][r] = -1e30f; ci[ni][r] = 0; }

    #pragma unroll
    for (int mi = 0; mi < 4; ++mi) {
        const int gi = rowBase + wr * 64 + mi * 16 + l15;
        rs[mi] = 0.f; rv[mi] = -1e30f; rj[mi] = 0;
        #pragma unroll
        for (int ni = 0; ni < 2; ++ni) {
            float4 vv;
            #pragma unroll
            for (int r = 0; r < 4; ++r) {
                float sv2 = (r == 0) ? s2v[ni].x : (r == 1) ? s2v[ni].y
                          : (r == 2) ? s2v[ni].z : s2v[ni].w;
                float dd = s1r[mi] + sv2 - 2.0f * acc[mi][ni][r];
                float v = -iT * __builtin_amdgcn_sqrtf(fmaxf(dd, 0.0f) + EPSQ);
                float e = __expf(v);
                ((float*)&vv)[r] = v;
                rs[mi] += e;
                if (v > rv[mi]) { rv[mi] = v; rj[mi] = colBase + colLoc0 + ni * 16 + r; }
                cs[ni][r] += e;
                if (v > cv[ni][r]) { cv[ni][r] = v; ci[ni][r] = gi; }
            }
            *(float4*)(aff_out + (size_t)gi * MCOLS + colBase + colLoc0 + ni * 16) = vv;
        }
    }

    // row reduce across col-quarters (lanes differing in bits 4,5), 2 steps
    #pragma unroll
    for (int mi = 0; mi < 4; ++mi) {
        float s = rs[mi], v = rv[mi]; int j = rj[mi];
        #pragma unroll
        for (int m = 16; m < 64; m <<= 1) {
            s += __shfl_xor(s, m, 64);
            float ov = __shfl_xor(v, m, 64);
            int oj = __shfl_xor(j, m, 64);
            if (ov > v || (ov == v && oj < j)) { v = ov; j = oj; }
        }
        if (lane < 16) {
            int idx = wr * 64 + mi * 16 + l15;
            atomicAdd(&lRowS[idx], s);
            atomicMax(&lRowK[idx], makeKey(v, j));
        }
    }

    // col reduce across l15 lanes (rows), 4 steps; mi already folded in-register
    #pragma unroll
    for (int ni = 0; ni < 2; ++ni)
        #pragma unroll
        for (int r = 0; r < 4; ++r) {
            float s = cs[ni][r], v = cv[ni][r]; int i = ci[ni][r];
            #pragma unroll
            for (int m = 1; m < 16; m <<= 1) {
                s += __shfl_xor(s, m, 64);
                float ov = __shfl_xor(v, m, 64);
                int oi = __shfl_xor(i, m, 64);
                if (ov > v || (ov == v && oi < i)) { v = ov; i = oi; }
            }
            if (l15 == 0) {
                int idx = colLoc0 + ni * 16 + r;
                atomicAdd(&lColS[idx], s);
                atomicMax(&lColK[idx], makeKey(v, i));
            }
        }
    __syncthreads();

    if (t < 128) {
        atomicAdd(&rowsum[rowBase + t], lRowS[t]);
        atomicMax(&rowkey[rowBase + t], lRowK[t]);
    } else if (t < 256) {
        int j = t - 128;
        atomicAdd(&colsum[colBase + j], lColS[j]);
        atomicMax(&colkey[colBase + j], lColK[j]);
    }
}

// ---------------- K2: per-row/col LSE + matches + cycle (merged) ----------------
__global__ __launch_bounds__(256) void finalize_small_kernel(
    const float* __restrict__ rowsum, const ull* __restrict__ rowkey,
    const float* __restrict__ colsum, const ull* __restrict__ colkey,
    float* __restrict__ rowlse, float* __restrict__ collse,
    float* __restrict__ out_matches, float* __restrict__ out_cyc)
{
    int i = blockIdx.x * 256 + threadIdx.x;      // N == M
    if (i >= NROWS) return;
    rowlse[i] = logf(rowsum[i]);
    collse[i] = logf(colsum[i]);
    int mi = decodeKeyIdx(rowkey[i]);
    out_matches[i]         = (float)i;
    out_matches[NROWS + i] = (float)mi;
    out_cyc[i] = (decodeKeyIdx(colkey[mi]) == i) ? 1.0f : 0.0f;
}

// ---------------- K3: dense_logp (in place) + dense_p ----------------
__global__ __launch_bounds__(256) void finalize_mat_kernel(
    float* __restrict__ aff_logp, float* __restrict__ p_out,
    const float* __restrict__ rowlse, const float* __restrict__ collse)
{
    size_t tid = (size_t)blockIdx.x * 256 + threadIdx.x;   // one float4 each
    int jq = (int)(tid % (MCOLS / 4));
    int i  = (int)(tid / (MCOLS / 4));
    float rl = rowlse[i];
    float4 cl = *(const float4*)(collse + jq * 4);
    float4 a  = *(float4*)(aff_logp + tid * 4);
    float4 o, p;
    o.x = (a.x - rl) + (a.x - cl.x); p.x = __expf(o.x);
    o.y = (a.y - rl) + (a.y - cl.y); p.y = __expf(o.y);
    o.z = (a.z - rl) + (a.z - cl.z); p.z = __expf(o.z);
    o.w = (a.w - rl) + (a.w - cl.w); p.w = __expf(o.w);
    *(float4*)(aff_logp + tid * 4) = o;
    *(float4*)(p_out + tid * 4)    = p;
}

extern "C" void kernel_launch(void* const* d_in, const int* in_sizes, int n_in,
                              void* d_out, int out_size, void* d_ws, size_t ws_size,
                              hipStream_t stream) {
    const float* d1   = (const float*)d_in[0];
    const float* d2   = (const float*)d_in[1];
    const float* invT = (const float*)d_in[2];

    float* out     = (float*)d_out;
    float* aff     = out;                              // dense_logp region
    float* pout    = out + (size_t)NROWS * MCOLS;
    float* matches = out + 2ull * NROWS * MCOLS;
    float* cyc     = matches + 2 * NROWS;

    char* ws = (char*)d_ws;
    float* rowsum = (float*)(ws + 0);
    float* colsum = (float*)(ws + 24576);
    ull*   rowkey = (ull*)(ws + 49152);
    ull*   colkey = (ull*)(ws + 98304);
    float* sq1    = (float*)(ws + 147456);
    float* sq2    = (float*)(ws + 172032);
    float* rowlse = (float*)(ws + 196608);
    float* collse = (float*)(ws + 221184);
    unsigned short* s1 = (unsigned short*)(ws + 270336);            // [N][256] bf16
    unsigned short* s2 = (unsigned short*)(ws + 270336 + 3145728);  // [M][256] bf16

    hipMemsetAsync(d_ws, 0, 147456, stream);           // rowsum/colsum/rowkey/colkey

    convert_kernel<<<(NROWS + MCOLS) / 4, 256, 0, stream>>>(d1, d2, s1, s2, sq1, sq2);

    dim3 grid(MCOLS / 128, NROWS / 128);
    gemm_affinity_kernel<<<grid, 512, 0, stream>>>(
        s1, s2, invT, sq1, sq2, aff, rowsum, colsum, rowkey, colkey);

    finalize_small_kernel<<<NROWS / 256, 256, 0, stream>>>(
        rowsum, rowkey, colsum, colkey, rowlse, collse, matches, cyc);

    finalize_mat_kernel<<<(size_t)NROWS * MCOLS / 4 / 256, 256, 0, stream>>>(
        aff, pout, rowlse, collse);
}